// Round 1
// baseline (2214.920 us; speedup 1.0000x reference)
//
#include <hip/hip_runtime.h>
#include <cmath>

#define SEQ    2048
#define DMODEL 1024
#define NHEADS 16
#define DK     64
#define MROWS  4096   // B*S

// ---------------------------------------------------------------------------
// GEMM: Y[M][N] = X[M][DMODEL] @ W[N][DMODEL]^T   (M=4096, N=1024)
// 64x64 tile, BK=16, 256 threads, each thread 4x4 micro-tile with
// CONSECUTIVE columns so RoPE even/odd pairs live in one thread.
// ---------------------------------------------------------------------------
template<int ROPE>
__global__ __launch_bounds__(256)
void gemm_xwt_kernel(const float* __restrict__ X, const float* __restrict__ W,
                     float* __restrict__ Y)
{
    __shared__ float Xs[16][68];   // [k][row], padded: 68*4=272B, 16B aligned
    __shared__ float Ws[16][68];   // [k][col]

    const int t  = threadIdx.x;
    const int tx = t & 15;         // column group (4 consecutive cols)
    const int ty = t >> 4;         // row group (4 consecutive rows)
    const int m0 = blockIdx.y * 64;
    const int n0 = blockIdx.x * 64;
    const int lr = t >> 2;         // 0..63 tile row for staging
    const int lc = (t & 3) * 4;    // k-subgroup for staging

    float acc[4][4] = {};

    const float* Xp = X + (size_t)(m0 + lr) * DMODEL + lc;
    const float* Wp = W + (size_t)(n0 + lr) * DMODEL + lc;

    for (int k0 = 0; k0 < DMODEL; k0 += 16) {
        float4 xa = *(const float4*)(Xp + k0);
        float4 wa = *(const float4*)(Wp + k0);
        __syncthreads();   // previous iteration's compute done before overwrite
        Xs[lc+0][lr]=xa.x; Xs[lc+1][lr]=xa.y; Xs[lc+2][lr]=xa.z; Xs[lc+3][lr]=xa.w;
        Ws[lc+0][lr]=wa.x; Ws[lc+1][lr]=wa.y; Ws[lc+2][lr]=wa.z; Ws[lc+3][lr]=wa.w;
        __syncthreads();
        #pragma unroll
        for (int kk = 0; kk < 16; ++kk) {
            float4 a = *(const float4*)&Xs[kk][ty*4];
            float4 b = *(const float4*)&Ws[kk][tx*4];
            float av[4] = {a.x, a.y, a.z, a.w};
            float bv[4] = {b.x, b.y, b.z, b.w};
            #pragma unroll
            for (int r = 0; r < 4; ++r)
                #pragma unroll
                for (int c = 0; c < 4; ++c)
                    acc[r][c] = fmaf(av[r], bv[c], acc[r][c]);
        }
    }

    const int c0 = n0 + tx*4;
    if (ROPE) {
        // columns c0..c0+3 = two (even,odd) RoPE pairs within a 64-dim head
        const float LOG_THETA_OVER_32 = 9.210340371976184f / 32.0f;
        const int i0 = ((c0) & 63) >> 1;     // c0 % 4 == 0 -> even
        const float f0 = __expf(-(float)(i0)     * LOG_THETA_OVER_32);
        const float f1 = __expf(-(float)(i0 + 1) * LOG_THETA_OVER_32);
        #pragma unroll
        for (int r = 0; r < 4; ++r) {
            const int   row = m0 + ty*4 + r;
            const float s   = (float)(row & (SEQ - 1));
            float s0, cc0, s1, cc1;
            sincosf(s * f0, &s0, &cc0);
            sincosf(s * f1, &s1, &cc1);
            const float e0 = acc[r][0], o0 = acc[r][1];
            const float e1 = acc[r][2], o1 = acc[r][3];
            float4 o;
            o.x = e0*cc0 - o0*s0;
            o.y = e0*s0  + o0*cc0;
            o.z = e1*cc1 - o1*s1;
            o.w = e1*s1  + o1*cc1;
            *(float4*)&Y[(size_t)row * DMODEL + c0] = o;
        }
    } else {
        #pragma unroll
        for (int r = 0; r < 4; ++r) {
            const int row = m0 + ty*4 + r;
            float4 o;
            o.x = acc[r][0]; o.y = acc[r][1]; o.z = acc[r][2]; o.w = acc[r][3];
            *(float4*)&Y[(size_t)row * DMODEL + c0] = o;
        }
    }
}

// ---------------------------------------------------------------------------
// Causal flash attention. Layouts [B, S, H*DK]. One block = 32 q rows of one
// (b,h). 64-key tiles, online softmax. O may alias Q (block writes exactly
// its own Q-read region, after all its Q reads).
// ---------------------------------------------------------------------------
__global__ __launch_bounds__(256)
void flash_attn_kernel(const float* __restrict__ Q, const float* __restrict__ K,
                       const float* __restrict__ V, float* __restrict__ O)
{
    __shared__ float Qs[32][68];
    __shared__ float Ks[64][68];
    __shared__ float Vs[64][68];
    __shared__ float Ss[32][68];
    __shared__ float alpha_s[32];
    __shared__ float l_s[32];

    const int t  = threadIdx.x;
    const int qb = blockIdx.x;
    const int bh = blockIdx.y;
    const int b  = bh >> 4;      // H = 16
    const int h  = bh & 15;

    // load Q tile: thread t -> row t>>3, cols (t&7)*8 .. +7
    {
        const int r = t >> 3;
        const int c = (t & 7) * 8;
        const float* p = Q + (size_t)(b*SEQ + qb*32 + r) * DMODEL + h*DK + c;
        *(float4*)&Qs[r][c]     = *(const float4*)(p);
        *(float4*)&Qs[r][c + 4] = *(const float4*)(p + 4);
    }

    float m_r = -INFINITY, l_r = 0.0f;   // live in threads t<32 (row = t)
    float oacc[8] = {0,0,0,0,0,0,0,0};
    const int ar  = t >> 3;        // owned row 0..31 (score & accum phases)
    const int ac  = (t & 7) * 8;   // owned 8 output cols
    const int sj0 = t & 7;         // score j offset (stride 8)
    const int qg  = qb*32 + ar;    // this row's query index
    const int ktmax = (qb*32 + 31) >> 6;

    for (int kt = 0; kt <= ktmax; ++kt) {
        __syncthreads();
        {   // stage K,V tile: thread t -> row t>>2, 16 cols at (t&3)*16
            const int r = t >> 2;
            const int c = (t & 3) * 16;
            const float* kp = K + (size_t)(b*SEQ + kt*64 + r) * DMODEL + h*DK + c;
            const float* vp = V + (size_t)(b*SEQ + kt*64 + r) * DMODEL + h*DK + c;
            #pragma unroll
            for (int q4 = 0; q4 < 16; q4 += 4) {
                *(float4*)&Ks[r][c + q4] = *(const float4*)(kp + q4);
                *(float4*)&Vs[r][c + q4] = *(const float4*)(vp + q4);
            }
        }
        __syncthreads();
        // scores: thread owns (ar, j = sj0 + 8*jj)
        #pragma unroll
        for (int jj = 0; jj < 8; ++jj) {
            const int j = sj0 + jj*8;
            float s = 0.0f;
            #pragma unroll
            for (int c4 = 0; c4 < 64; c4 += 4) {
                float4 qa = *(const float4*)&Qs[ar][c4];
                float4 ka = *(const float4*)&Ks[j][c4];
                s += qa.x*ka.x + qa.y*ka.y + qa.z*ka.z + qa.w*ka.w;
            }
            s *= 0.125f;                       // 1/sqrt(64)
            if (kt*64 + j > qg) s = -INFINITY; // causal (tril inclusive)
            Ss[ar][j] = s;
        }
        __syncthreads();
        // online softmax: thread r (<32) owns row r
        if (t < 32) {
            float tm = -INFINITY;
            #pragma unroll
            for (int j = 0; j < 64; ++j) tm = fmaxf(tm, Ss[t][j]);
            const float mnew = fmaxf(m_r, tm);
            const float a = (m_r == -INFINITY) ? 0.0f : __expf(m_r - mnew);
            float sum = 0.0f;
            #pragma unroll
            for (int j = 0; j < 64; ++j) {
                const float p = __expf(Ss[t][j] - mnew);  // exp(-inf)=0 for masked
                Ss[t][j] = p;
                sum += p;
            }
            l_r = l_r * a + sum;
            m_r = mnew;
            alpha_s[t] = a;
            l_s[t] = l_r;
        }
        __syncthreads();
        // accumulate O
        const float av = alpha_s[ar];
        #pragma unroll
        for (int c = 0; c < 8; ++c) oacc[c] *= av;
        for (int j = 0; j < 64; ++j) {
            const float p = Ss[ar][j];
            float4 v0 = *(const float4*)&Vs[j][ac];
            float4 v1 = *(const float4*)&Vs[j][ac + 4];
            oacc[0] = fmaf(p, v0.x, oacc[0]); oacc[1] = fmaf(p, v0.y, oacc[1]);
            oacc[2] = fmaf(p, v0.z, oacc[2]); oacc[3] = fmaf(p, v0.w, oacc[3]);
            oacc[4] = fmaf(p, v1.x, oacc[4]); oacc[5] = fmaf(p, v1.y, oacc[5]);
            oacc[6] = fmaf(p, v1.z, oacc[6]); oacc[7] = fmaf(p, v1.w, oacc[7]);
        }
    }

    const float linv = 1.0f / l_s[ar];
    float* op = O + (size_t)(b*SEQ + qb*32 + ar) * DMODEL + h*DK + ac;
    float4 r0, r1;
    r0.x = oacc[0]*linv; r0.y = oacc[1]*linv; r0.z = oacc[2]*linv; r0.w = oacc[3]*linv;
    r1.x = oacc[4]*linv; r1.y = oacc[5]*linv; r1.z = oacc[6]*linv; r1.w = oacc[7]*linv;
    *(float4*)(op)     = r0;
    *(float4*)(op + 4) = r1;
}

// ---------------------------------------------------------------------------
extern "C" void kernel_launch(void* const* d_in, const int* in_sizes, int n_in,
                              void* d_out, int out_size, void* d_ws, size_t ws_size,
                              hipStream_t stream)
{
    const float* x  = (const float*)d_in[0];
    const float* Wq = (const float*)d_in[1];
    const float* Wk = (const float*)d_in[2];
    const float* Wv = (const float*)d_in[3];
    const float* Wo = (const float*)d_in[4];
    float* out = (float*)d_out;

    const size_t TENS = (size_t)MROWS * DMODEL;  // 4,194,304 floats
    float* Q = (float*)d_ws;
    float* K = Q + TENS;
    float* V = K + TENS;

    dim3 gg(DMODEL / 64, MROWS / 64);  // (16, 64)
    dim3 gb(256);

    gemm_xwt_kernel<1><<<gg, gb, 0, stream>>>(x, Wq, Q);   // Q proj + RoPE
    gemm_xwt_kernel<1><<<gg, gb, 0, stream>>>(x, Wk, K);   // K proj + RoPE
    gemm_xwt_kernel<0><<<gg, gb, 0, stream>>>(x, Wv, V);   // V proj

    dim3 ag(SEQ / 32, 2 * NHEADS);     // (64, 32)
    flash_attn_kernel<<<ag, gb, 0, stream>>>(Q, K, V, /*O aliases Q*/ Q);

    gemm_xwt_kernel<0><<<gg, gb, 0, stream>>>(Q, Wo, out); // output proj
}

// Round 2
// 768.059 us; speedup vs baseline: 2.8838x; 2.8838x over previous
//
#include <hip/hip_runtime.h>
#include <cmath>

#define SEQ    2048
#define DMODEL 1024
#define NHEADS 16
#define DK     64
#define MROWS  4096   // B*S
#define PITCH  72     // LDS row pitch in bf16 elems (144B: 2-way-conflict-free, 16B aligned)

typedef __bf16 bf16x8 __attribute__((ext_vector_type(8)));
typedef float  f32x4  __attribute__((ext_vector_type(4)));

__device__ __forceinline__ unsigned short f2bf(float f) {
    union { float f; unsigned u; } v; v.f = f;
    unsigned r = v.u + 0x7fffu + ((v.u >> 16) & 1u);   // RNE
    return (unsigned short)(r >> 16);
}

// ---------------------------------------------------------------------------
// GEMM: Y[M][N] = X[M][DMODEL] @ W[N][DMODEL]^T  (fp32 compute)
// BF16OUT: write bf16 (QKV path).  ROPE: fuse RoPE into epilogue (Q,K).
// ---------------------------------------------------------------------------
template<int ROPE, int BF16OUT>
__global__ __launch_bounds__(256)
void gemm_xwt_kernel(const float* __restrict__ X, const float* __restrict__ W,
                     void* __restrict__ Yv)
{
    __shared__ float Xs[16][68];
    __shared__ float Ws[16][68];

    const int t  = threadIdx.x;
    const int tx = t & 15;
    const int ty = t >> 4;
    const int m0 = blockIdx.y * 64;
    const int n0 = blockIdx.x * 64;
    const int lr = t >> 2;
    const int lc = (t & 3) * 4;

    float acc[4][4] = {};

    const float* Xp = X + (size_t)(m0 + lr) * DMODEL + lc;
    const float* Wp = W + (size_t)(n0 + lr) * DMODEL + lc;

    for (int k0 = 0; k0 < DMODEL; k0 += 16) {
        float4 xa = *(const float4*)(Xp + k0);
        float4 wa = *(const float4*)(Wp + k0);
        __syncthreads();
        Xs[lc+0][lr]=xa.x; Xs[lc+1][lr]=xa.y; Xs[lc+2][lr]=xa.z; Xs[lc+3][lr]=xa.w;
        Ws[lc+0][lr]=wa.x; Ws[lc+1][lr]=wa.y; Ws[lc+2][lr]=wa.z; Ws[lc+3][lr]=wa.w;
        __syncthreads();
        #pragma unroll
        for (int kk = 0; kk < 16; ++kk) {
            float4 a = *(const float4*)&Xs[kk][ty*4];
            float4 b = *(const float4*)&Ws[kk][tx*4];
            float av[4] = {a.x, a.y, a.z, a.w};
            float bv[4] = {b.x, b.y, b.z, b.w};
            #pragma unroll
            for (int r = 0; r < 4; ++r)
                #pragma unroll
                for (int c = 0; c < 4; ++c)
                    acc[r][c] = fmaf(av[r], bv[c], acc[r][c]);
        }
    }

    const int c0 = n0 + tx*4;
    #pragma unroll
    for (int r = 0; r < 4; ++r) {
        const int row = m0 + ty*4 + r;
        float o0, o1, o2, o3;
        if (ROPE) {
            const float LOG_THETA_OVER_32 = 9.210340371976184f / 32.0f;
            const int i0 = (c0 & 63) >> 1;
            const float f0 = __expf(-(float)(i0)     * LOG_THETA_OVER_32);
            const float f1 = __expf(-(float)(i0 + 1) * LOG_THETA_OVER_32);
            const float s  = (float)(row & (SEQ - 1));
            float s0, cc0, s1, cc1;
            sincosf(s * f0, &s0, &cc0);
            sincosf(s * f1, &s1, &cc1);
            const float e0 = acc[r][0], od0 = acc[r][1];
            const float e1 = acc[r][2], od1 = acc[r][3];
            o0 = e0*cc0 - od0*s0;
            o1 = e0*s0  + od0*cc0;
            o2 = e1*cc1 - od1*s1;
            o3 = e1*s1  + od1*cc1;
        } else {
            o0 = acc[r][0]; o1 = acc[r][1]; o2 = acc[r][2]; o3 = acc[r][3];
        }
        if (BF16OUT) {
            unsigned short* Yb = (unsigned short*)Yv;
            ushort4 ov;
            ov.x = f2bf(o0); ov.y = f2bf(o1); ov.z = f2bf(o2); ov.w = f2bf(o3);
            *(ushort4*)&Yb[(size_t)row * DMODEL + c0] = ov;
        } else {
            float* Yf = (float*)Yv;
            float4 ov; ov.x=o0; ov.y=o1; ov.z=o2; ov.w=o3;
            *(float4*)&Yf[(size_t)row * DMODEL + c0] = ov;
        }
    }
}

// ---------------------------------------------------------------------------
// MFMA flash attention (bf16 in, fp32 accum). One block = 64 q rows of one
// (b,h); 4 waves x 16 rows; 64-key tiles; mfma_f32_16x16x32_bf16.
// Layouts in global: Q/K/V bf16 [B*S][H*DK]; O fp32 [B*S][H*DK].
// ---------------------------------------------------------------------------
__global__ __launch_bounds__(256)
void flash_mfma_kernel(const unsigned short* __restrict__ Qb,
                       const unsigned short* __restrict__ Kb,
                       const unsigned short* __restrict__ Vb,
                       float* __restrict__ Oc)
{
    __shared__ unsigned short Kt[64 * PITCH];  // K tile row-major [s][d]
    __shared__ unsigned short Vt[64 * PITCH];  // V tile transposed [d][s]
    __shared__ unsigned short Ps[64 * PITCH];  // Q staging, then P round-trip

    const int t    = threadIdx.x;
    const int w    = t >> 6;          // wave 0..3
    const int lane = t & 63;
    const int lq   = lane >> 4;       // quad 0..3
    const int ln   = lane & 15;
    const int qb   = blockIdx.x;      // q-tile 0..31
    const int bh   = blockIdx.y;
    const int b    = bh >> 4;
    const int h    = bh & 15;

    const int sr = t >> 2;            // staging row 0..63
    const int sc = (t & 3) * 16;      // staging col 0,16,32,48

    // --- stage Q tile -> Ps, load per-wave A fragments into registers
    {
        const unsigned short* qp =
            Qb + (size_t)(b*SEQ + qb*64 + sr) * DMODEL + h*DK + sc;
        *(float4*)&Ps[sr*PITCH + sc]     = *(const float4*)qp;
        *(float4*)&Ps[sr*PITCH + sc + 8] = *(const float4*)(qp + 8);
    }
    __syncthreads();
    bf16x8 qfrag0, qfrag1;
    {
        const int qrow = w*16 + ln;
        qfrag0 = *(const bf16x8*)&Ps[qrow*PITCH + lq*8];
        qfrag1 = *(const bf16x8*)&Ps[qrow*PITCH + 32 + lq*8];
    }

    f32x4 oacc[4];
    #pragma unroll
    for (int dt = 0; dt < 4; ++dt)
        #pragma unroll
        for (int r = 0; r < 4; ++r) oacc[dt][r] = 0.0f;

    float m_r[4], l_r[4];
    #pragma unroll
    for (int r = 0; r < 4; ++r) { m_r[r] = -INFINITY; l_r[r] = 0.0f; }

    const int row_g = qb*64 + w*16 + lq*4;   // + r = global q row

    for (int kt = 0; kt <= qb; ++kt) {
        __syncthreads();
        // --- stage K tile (row-major) and V tile (transposed)
        {
            const unsigned short* kp =
                Kb + (size_t)(b*SEQ + kt*64 + sr) * DMODEL + h*DK + sc;
            *(float4*)&Kt[sr*PITCH + sc]     = *(const float4*)kp;
            *(float4*)&Kt[sr*PITCH + sc + 8] = *(const float4*)(kp + 8);
            const unsigned short* vp =
                Vb + (size_t)(b*SEQ + kt*64 + sr) * DMODEL + h*DK + sc;
            unsigned short vtmp[16];
            *(float4*)&vtmp[0] = *(const float4*)vp;
            *(float4*)&vtmp[8] = *(const float4*)(vp + 8);
            #pragma unroll
            for (int i = 0; i < 16; ++i)
                Vt[(sc + i)*PITCH + sr] = vtmp[i];
        }
        __syncthreads();

        // --- S = Q K^T (per wave: 16 rows x 64 cols)
        f32x4 sacc[4];
        #pragma unroll
        for (int nt = 0; nt < 4; ++nt) {
            #pragma unroll
            for (int r = 0; r < 4; ++r) sacc[nt][r] = 0.0f;
            bf16x8 kf0 = *(const bf16x8*)&Kt[(nt*16 + ln)*PITCH + lq*8];
            bf16x8 kf1 = *(const bf16x8*)&Kt[(nt*16 + ln)*PITCH + 32 + lq*8];
            sacc[nt] = __builtin_amdgcn_mfma_f32_16x16x32_bf16(qfrag0, kf0, sacc[nt], 0, 0, 0);
            sacc[nt] = __builtin_amdgcn_mfma_f32_16x16x32_bf16(qfrag1, kf1, sacc[nt], 0, 0, 0);
        }

        // --- online softmax (registers + shfl within 16-lane groups)
        const bool diag = (kt == qb);
        #pragma unroll
        for (int r = 0; r < 4; ++r) {
            float s0 = sacc[0][r] * 0.125f;
            float s1 = sacc[1][r] * 0.125f;
            float s2 = sacc[2][r] * 0.125f;
            float s3 = sacc[3][r] * 0.125f;
            if (diag) {
                const int rg = row_g + r;
                const int c0 = kt*64 + ln;
                if (c0      > rg) s0 = -INFINITY;
                if (c0 + 16 > rg) s1 = -INFINITY;
                if (c0 + 32 > rg) s2 = -INFINITY;
                if (c0 + 48 > rg) s3 = -INFINITY;
            }
            float tm = fmaxf(fmaxf(s0, s1), fmaxf(s2, s3));
            #pragma unroll
            for (int off = 1; off < 16; off <<= 1)
                tm = fmaxf(tm, __shfl_xor(tm, off, 16));
            const float mnew  = fmaxf(m_r[r], tm);
            const float alpha = __expf(m_r[r] - mnew);  // exp(-inf)=0 first time
            const float p0 = __expf(s0 - mnew);
            const float p1 = __expf(s1 - mnew);
            const float p2 = __expf(s2 - mnew);
            const float p3 = __expf(s3 - mnew);
            float sum = p0 + p1 + p2 + p3;
            #pragma unroll
            for (int off = 1; off < 16; off <<= 1)
                sum += __shfl_xor(sum, off, 16);
            l_r[r] = l_r[r] * alpha + sum;
            m_r[r] = mnew;
            #pragma unroll
            for (int dt = 0; dt < 4; ++dt) oacc[dt][r] *= alpha;
            const int pbase = (w*16 + lq*4 + r)*PITCH + ln;
            Ps[pbase]      = f2bf(p0);
            Ps[pbase + 16] = f2bf(p1);
            Ps[pbase + 32] = f2bf(p2);
            Ps[pbase + 48] = f2bf(p3);
        }
        __syncthreads();   // P write -> P read (and keeps waves in step)

        // --- O += P V
        {
            bf16x8 pa0 = *(const bf16x8*)&Ps[(w*16 + ln)*PITCH + lq*8];
            bf16x8 pa1 = *(const bf16x8*)&Ps[(w*16 + ln)*PITCH + 32 + lq*8];
            #pragma unroll
            for (int dt = 0; dt < 4; ++dt) {
                bf16x8 v0 = *(const bf16x8*)&Vt[(dt*16 + ln)*PITCH + lq*8];
                bf16x8 v1 = *(const bf16x8*)&Vt[(dt*16 + ln)*PITCH + 32 + lq*8];
                oacc[dt] = __builtin_amdgcn_mfma_f32_16x16x32_bf16(pa0, v0, oacc[dt], 0, 0, 0);
                oacc[dt] = __builtin_amdgcn_mfma_f32_16x16x32_bf16(pa1, v1, oacc[dt], 0, 0, 0);
            }
        }
    }

    // --- epilogue: normalize and store fp32
    #pragma unroll
    for (int r = 0; r < 4; ++r) {
        const float linv = 1.0f / l_r[r];
        const int row = qb*64 + w*16 + lq*4 + r;
        float* op = Oc + (size_t)(b*SEQ + row) * DMODEL + h*DK;
        #pragma unroll
        for (int dt = 0; dt < 4; ++dt)
            op[dt*16 + ln] = oacc[dt][r] * linv;
    }
}

// ---------------------------------------------------------------------------
extern "C" void kernel_launch(void* const* d_in, const int* in_sizes, int n_in,
                              void* d_out, int out_size, void* d_ws, size_t ws_size,
                              hipStream_t stream)
{
    const float* x  = (const float*)d_in[0];
    const float* Wq = (const float*)d_in[1];
    const float* Wk = (const float*)d_in[2];
    const float* Wv = (const float*)d_in[3];
    const float* Wo = (const float*)d_in[4];
    float* out = (float*)d_out;

    const size_t TENS = (size_t)MROWS * DMODEL;
    unsigned short* Qb = (unsigned short*)d_ws;
    unsigned short* Kb = Qb + TENS;
    unsigned short* Vb = Kb + TENS;
    float*          Oc = (float*)(Vb + TENS);

    dim3 gg(DMODEL / 64, MROWS / 64);
    dim3 gb(256);

    gemm_xwt_kernel<1,1><<<gg, gb, 0, stream>>>(x, Wq, Qb);  // Q proj + RoPE -> bf16
    gemm_xwt_kernel<1,1><<<gg, gb, 0, stream>>>(x, Wk, Kb);  // K proj + RoPE -> bf16
    gemm_xwt_kernel<0,1><<<gg, gb, 0, stream>>>(x, Wv, Vb);  // V proj -> bf16

    dim3 ag(SEQ / 64, 2 * NHEADS);
    flash_mfma_kernel<<<ag, gb, 0, stream>>>(Qb, Kb, Vb, Oc);

    gemm_xwt_kernel<0,0><<<gg, gb, 0, stream>>>(Oc, Wo, out);  // O proj fp32
}

// Round 3
// 240.568 us; speedup vs baseline: 9.2070x; 3.1927x over previous
//
#include <hip/hip_runtime.h>
#include <cmath>

#define SEQ    2048
#define DMODEL 1024
#define NHEADS 16
#define DK     64
#define MROWS  4096   // B*S
#define PITCH  72     // flash LDS pitch (bf16 elems)

typedef __bf16 bf16x8 __attribute__((ext_vector_type(8)));
typedef float  f32x4  __attribute__((ext_vector_type(4)));

__device__ __forceinline__ unsigned short f2bf(float f) {
    union { float f; unsigned u; } v; v.f = f;
    unsigned r = v.u + 0x7fffu + ((v.u >> 16) & 1u);   // RNE
    return (unsigned short)(r >> 16);
}

__device__ __forceinline__ void async16(const unsigned short* g, unsigned short* l) {
    __builtin_amdgcn_global_load_lds(
        (const __attribute__((address_space(1))) unsigned int*)(g),
        (__attribute__((address_space(3))) unsigned int*)(l),
        16, 0, 0);
}

// ---------------------------------------------------------------------------
// fp32 -> bf16 conversion of x, Wq|Wk|Wv (packed), Wo
// ---------------------------------------------------------------------------
__global__ __launch_bounds__(256)
void convert_kernel(const float* __restrict__ x,
                    const float* __restrict__ wq, const float* __restrict__ wk,
                    const float* __restrict__ wv, const float* __restrict__ wo,
                    unsigned short* __restrict__ xb,
                    unsigned short* __restrict__ wqkvb,
                    unsigned short* __restrict__ wob)
{
    const unsigned e = (blockIdx.x * 256u + threadIdx.x) * 8u;
    const float* src; unsigned short* dst; unsigned off;
    if      (e < 4194304u) { src = x;  dst = xb;             off = e;            }
    else if (e < 5242880u) { src = wq; dst = wqkvb;          off = e - 4194304u; }
    else if (e < 6291456u) { src = wk; dst = wqkvb+1048576u; off = e - 5242880u; }
    else if (e < 7340032u) { src = wv; dst = wqkvb+2097152u; off = e - 6291456u; }
    else                   { src = wo; dst = wob;            off = e - 7340032u; }
    float4 a = *(const float4*)(src + off);
    float4 b = *(const float4*)(src + off + 4);
    ushort4 u0, u1;
    u0.x=f2bf(a.x); u0.y=f2bf(a.y); u0.z=f2bf(a.z); u0.w=f2bf(a.w);
    u1.x=f2bf(b.x); u1.y=f2bf(b.y); u1.z=f2bf(b.z); u1.w=f2bf(b.w);
    *(ushort4*)(dst + off)     = u0;
    *(ushort4*)(dst + off + 4) = u1;
}

// ---------------------------------------------------------------------------
// bf16 MFMA GEMM: Y[M][NCOLS] = A[M][1024] @ B[NCOLS][1024]^T
// m97 structure: 128x128 tile, BK=32, global_load_lds w=16, 2-barrier K-loop.
// XOR k-slot swizzle breaks frag-read bank conflicts (global src addr is
// per-lane free; LDS dest is lane-ordered).
// ROPE: applied where global col < 2048 (Q,K regions of the QKV gemm).
// ---------------------------------------------------------------------------
template<int NCOLS, int ROPE, int BF16OUT>
__global__ __launch_bounds__(256)
void gemm_mfma_bt(const unsigned short* __restrict__ A,
                  const unsigned short* __restrict__ B,
                  void* __restrict__ Yv)
{
    __shared__ unsigned short As[128*32];   // 8 KB, no padding (load_lds)
    __shared__ unsigned short Bs[128*32];

    const int t    = threadIdx.x;
    const int w    = t >> 6;
    const int lane = t & 63;
    const int lq   = lane >> 4;
    const int ln   = lane & 15;
    const int wr   = w >> 1;
    const int wc   = w & 1;
    const int m0   = blockIdx.y * 128;
    const int n0   = blockIdx.x * 128;

    // staging: per wave, 2 chunks of 16 rows x 32 k each for A and B
    const int srow  = lane >> 2;         // 0..15
    const int kslot = lane & 3;          // phys 8-elem slot
    const int kk    = kslot ^ ((srow >> 1) & 3);   // logical k-group (swizzle)

    const unsigned short* ga0 = A + (size_t)(m0 + w*16 + srow) * 1024 + kk*8;
    const unsigned short* gb0 = B + (size_t)(n0 + w*16 + srow) * 1024 + kk*8;
    unsigned short* lA = As + w*512;     // wave-uniform 1KB chunk base
    unsigned short* lB = Bs + w*512;

    f32x4 acc[4][4];
    #pragma unroll
    for (int mt = 0; mt < 4; ++mt)
        #pragma unroll
        for (int nt = 0; nt < 4; ++nt)
            #pragma unroll
            for (int r = 0; r < 4; ++r) acc[mt][nt][r] = 0.0f;

    const int fslot = (lq ^ ((ln >> 1) & 3)) * 8;   // swizzled frag k-slot

    for (int k0 = 0; k0 < 1024; k0 += 32) {
        __syncthreads();                     // prev tile fully consumed
        async16(ga0 + k0,           lA);
        async16(ga0 + 64*1024 + k0, lA + 2048);
        async16(gb0 + k0,           lB);
        async16(gb0 + 64*1024 + k0, lB + 2048);
        __syncthreads();                     // loads drained (vmcnt before barrier)
        bf16x8 af[4], bf[4];
        #pragma unroll
        for (int i = 0; i < 4; ++i) {
            af[i] = *(const bf16x8*)&As[(wr*64 + i*16 + ln)*32 + fslot];
            bf[i] = *(const bf16x8*)&Bs[(wc*64 + i*16 + ln)*32 + fslot];
        }
        #pragma unroll
        for (int mt = 0; mt < 4; ++mt)
            #pragma unroll
            for (int nt = 0; nt < 4; ++nt)
                acc[mt][nt] = __builtin_amdgcn_mfma_f32_16x16x32_bf16(
                                  af[mt], bf[nt], acc[mt][nt], 0, 0, 0);
    }

    // epilogue: C layout col = ln, row = lq*4 + r (per 16x16 tile)
    unsigned short* Yb = (unsigned short*)Yv;
    float*          Yf = (float*)Yv;
    const bool doRope = ROPE && (n0 < 2048);
    const float LOG_T = 9.210340371976184f / 32.0f;
    #pragma unroll
    for (int nt = 0; nt < 4; ++nt) {
        const int col = n0 + wc*64 + nt*16 + ln;
        float fr = 0.0f;
        if (doRope) fr = __expf(-(float)((col & 63) >> 1) * LOG_T);
        #pragma unroll
        for (int mt = 0; mt < 4; ++mt) {
            const int row0 = m0 + wr*64 + mt*16 + lq*4;
            #pragma unroll
            for (int r = 0; r < 4; ++r) {
                const float v = acc[mt][nt][r];
                float outv;
                if (doRope) {
                    float sn, cs;
                    __sincosf((float)((row0 + r) & (SEQ - 1)) * fr, &sn, &cs);
                    const float p = __shfl_xor(v, 1);
                    outv = ((ln & 1) == 0) ? (v*cs - p*sn) : (p*sn + v*cs);
                } else {
                    outv = v;
                }
                const size_t yi = (size_t)(row0 + r) * NCOLS + col;
                if (BF16OUT) Yb[yi] = f2bf(outv);
                else         Yf[yi] = outv;
            }
        }
    }
}

// ---------------------------------------------------------------------------
// MFMA flash attention over packed QKV [4096][3072] bf16 -> Ob [4096][1024] bf16
// Block = 64 q rows of one (b,h); 4 waves x 16 rows; 64-key tiles.
// Heavy q-tiles dispatched first (qb reversed on grid.y).
// ---------------------------------------------------------------------------
__global__ __launch_bounds__(256)
void flash_mfma_kernel(const unsigned short* __restrict__ QKV,
                       unsigned short* __restrict__ Ob)
{
    __shared__ unsigned short Kt[64 * PITCH];
    __shared__ unsigned short Vt[64 * PITCH];   // transposed [d][s]
    __shared__ unsigned short Ps[64 * PITCH];

    const int t    = threadIdx.x;
    const int w    = t >> 6;
    const int lane = t & 63;
    const int lq   = lane >> 4;
    const int ln   = lane & 15;
    const int bh   = blockIdx.x;
    const int qb   = (int)gridDim.y - 1 - blockIdx.y;   // heavy first
    const int b    = bh >> 4;
    const int h    = bh & 15;
    const int LD   = 3072;

    const unsigned short* Qg = QKV + h*DK;
    const unsigned short* Kg = QKV + 1024 + h*DK;
    const unsigned short* Vg = QKV + 2048 + h*DK;

    const int sr = t >> 2;            // K/Q staging row
    const int sc = (t & 3) * 16;      // K/Q staging col
    const int vr = t & 63;            // V staging row (lane-contiguous writes)

    {   // stage Q tile
        const unsigned short* qp = Qg + (size_t)(b*SEQ + qb*64 + sr) * LD + sc;
        *(float4*)&Ps[sr*PITCH + sc]     = *(const float4*)qp;
        *(float4*)&Ps[sr*PITCH + sc + 8] = *(const float4*)(qp + 8);
    }
    __syncthreads();
    bf16x8 qfrag0, qfrag1;
    {
        const int qrow = w*16 + ln;
        qfrag0 = *(const bf16x8*)&Ps[qrow*PITCH + lq*8];
        qfrag1 = *(const bf16x8*)&Ps[qrow*PITCH + 32 + lq*8];
    }

    f32x4 oacc[4];
    #pragma unroll
    for (int dt = 0; dt < 4; ++dt)
        #pragma unroll
        for (int r = 0; r < 4; ++r) oacc[dt][r] = 0.0f;

    float m_r[4], l_r[4];
    #pragma unroll
    for (int r = 0; r < 4; ++r) { m_r[r] = -INFINITY; l_r[r] = 0.0f; }

    const int row_g = qb*64 + w*16 + lq*4;

    for (int kt = 0; kt <= qb; ++kt) {
        __syncthreads();
        {   // stage K (row-major) and V (transposed, lane-contiguous writes)
            const unsigned short* kp = Kg + (size_t)(b*SEQ + kt*64 + sr) * LD + sc;
            *(float4*)&Kt[sr*PITCH + sc]     = *(const float4*)kp;
            *(float4*)&Kt[sr*PITCH + sc + 8] = *(const float4*)(kp + 8);
            const unsigned short* vp = Vg + (size_t)(b*SEQ + kt*64 + vr) * LD + w*16;
            unsigned short vtmp[16];
            *(float4*)&vtmp[0] = *(const float4*)vp;
            *(float4*)&vtmp[8] = *(const float4*)(vp + 8);
            #pragma unroll
            for (int i = 0; i < 16; ++i)
                Vt[(w*16 + i)*PITCH + vr] = vtmp[i];
        }
        __syncthreads();

        // S = Q K^T
        f32x4 sacc[4];
        #pragma unroll
        for (int nt = 0; nt < 4; ++nt) {
            #pragma unroll
            for (int r = 0; r < 4; ++r) sacc[nt][r] = 0.0f;
            bf16x8 kf0 = *(const bf16x8*)&Kt[(nt*16 + ln)*PITCH + lq*8];
            bf16x8 kf1 = *(const bf16x8*)&Kt[(nt*16 + ln)*PITCH + 32 + lq*8];
            sacc[nt] = __builtin_amdgcn_mfma_f32_16x16x32_bf16(qfrag0, kf0, sacc[nt], 0, 0, 0);
            sacc[nt] = __builtin_amdgcn_mfma_f32_16x16x32_bf16(qfrag1, kf1, sacc[nt], 0, 0, 0);
        }

        // online softmax
        const bool diag = (kt == qb);
        #pragma unroll
        for (int r = 0; r < 4; ++r) {
            float s0 = sacc[0][r] * 0.125f;
            float s1 = sacc[1][r] * 0.125f;
            float s2 = sacc[2][r] * 0.125f;
            float s3 = sacc[3][r] * 0.125f;
            if (diag) {
                const int rg = row_g + r;
                const int c0 = kt*64 + ln;
                if (c0      > rg) s0 = -INFINITY;
                if (c0 + 16 > rg) s1 = -INFINITY;
                if (c0 + 32 > rg) s2 = -INFINITY;
                if (c0 + 48 > rg) s3 = -INFINITY;
            }
            float tm = fmaxf(fmaxf(s0, s1), fmaxf(s2, s3));
            #pragma unroll
            for (int off = 1; off < 16; off <<= 1)
                tm = fmaxf(tm, __shfl_xor(tm, off, 16));
            const float mnew  = fmaxf(m_r[r], tm);
            const float alpha = __expf(m_r[r] - mnew);
            const float p0 = __expf(s0 - mnew);
            const float p1 = __expf(s1 - mnew);
            const float p2 = __expf(s2 - mnew);
            const float p3 = __expf(s3 - mnew);
            float sum = p0 + p1 + p2 + p3;
            #pragma unroll
            for (int off = 1; off < 16; off <<= 1)
                sum += __shfl_xor(sum, off, 16);
            l_r[r] = l_r[r] * alpha + sum;
            m_r[r] = mnew;
            #pragma unroll
            for (int dt = 0; dt < 4; ++dt) oacc[dt][r] *= alpha;
            const int pbase = (w*16 + lq*4 + r)*PITCH + ln;
            Ps[pbase]      = f2bf(p0);
            Ps[pbase + 16] = f2bf(p1);
            Ps[pbase + 32] = f2bf(p2);
            Ps[pbase + 48] = f2bf(p3);
        }
        __syncthreads();

        // O += P V
        {
            bf16x8 pa0 = *(const bf16x8*)&Ps[(w*16 + ln)*PITCH + lq*8];
            bf16x8 pa1 = *(const bf16x8*)&Ps[(w*16 + ln)*PITCH + 32 + lq*8];
            #pragma unroll
            for (int dt = 0; dt < 4; ++dt) {
                bf16x8 v0 = *(const bf16x8*)&Vt[(dt*16 + ln)*PITCH + lq*8];
                bf16x8 v1 = *(const bf16x8*)&Vt[(dt*16 + ln)*PITCH + 32 + lq*8];
                oacc[dt] = __builtin_amdgcn_mfma_f32_16x16x32_bf16(pa0, v0, oacc[dt], 0, 0, 0);
                oacc[dt] = __builtin_amdgcn_mfma_f32_16x16x32_bf16(pa1, v1, oacc[dt], 0, 0, 0);
            }
        }
    }

    // epilogue -> bf16
    #pragma unroll
    for (int r = 0; r < 4; ++r) {
        const float linv = 1.0f / l_r[r];
        const int row = qb*64 + w*16 + lq*4 + r;
        unsigned short* op = Ob + (size_t)(b*SEQ + row) * DMODEL + h*DK;
        #pragma unroll
        for (int dt = 0; dt < 4; ++dt)
            op[dt*16 + ln] = f2bf(oacc[dt][r] * linv);
    }
}

// ---------------------------------------------------------------------------
extern "C" void kernel_launch(void* const* d_in, const int* in_sizes, int n_in,
                              void* d_out, int out_size, void* d_ws, size_t ws_size,
                              hipStream_t stream)
{
    const float* x  = (const float*)d_in[0];
    const float* Wq = (const float*)d_in[1];
    const float* Wk = (const float*)d_in[2];
    const float* Wv = (const float*)d_in[3];
    const float* Wo = (const float*)d_in[4];
    float* out = (float*)d_out;

    unsigned short* xb    = (unsigned short*)d_ws;   //  4M elems
    unsigned short* wqkvb = xb + 4194304;            //  3M
    unsigned short* wob   = wqkvb + 3145728;         //  1M
    unsigned short* qkv   = wob + 1048576;           // 12M  [4096][3072]
    unsigned short* ob    = qkv + 12582912;          //  4M  [4096][1024]

    convert_kernel<<<4096, 256, 0, stream>>>(x, Wq, Wk, Wv, Wo, xb, wqkvb, wob);

    gemm_mfma_bt<3072, 1, 1><<<dim3(24, 32), 256, 0, stream>>>(xb, wqkvb, qkv);

    flash_mfma_kernel<<<dim3(32, 32), 256, 0, stream>>>(qkv, ob);

    gemm_mfma_bt<1024, 0, 0><<<dim3(8, 32), 256, 0, stream>>>(ob, wob, out);
}

// Round 4
// 217.319 us; speedup vs baseline: 10.1920x; 1.1070x over previous
//
#include <hip/hip_runtime.h>
#include <cmath>

#define SEQ    2048
#define DMODEL 1024
#define NHEADS 16
#define DK     64
#define MROWS  4096   // B*S
#define PITCH  72     // flash LDS pitch (bf16 elems)

typedef __bf16 bf16x8 __attribute__((ext_vector_type(8)));
typedef float  f32x4  __attribute__((ext_vector_type(4)));
typedef short  s16x4  __attribute__((ext_vector_type(4)));

__device__ __forceinline__ unsigned short f2bf(float f) {
    union { float f; unsigned u; } v; v.f = f;
    unsigned r = v.u + 0x7fffu + ((v.u >> 16) & 1u);   // RNE
    return (unsigned short)(r >> 16);
}

__device__ __forceinline__ void async16(const unsigned short* g, unsigned short* l) {
    __builtin_amdgcn_global_load_lds(
        (const __attribute__((address_space(1))) unsigned int*)(g),
        (__attribute__((address_space(3))) unsigned int*)(l),
        16, 0, 0);
}

// ---------------------------------------------------------------------------
// fp32 -> bf16 conversion of x, Wq|Wk|Wv (packed), Wo
// ---------------------------------------------------------------------------
__global__ __launch_bounds__(256)
void convert_kernel(const float* __restrict__ x,
                    const float* __restrict__ wq, const float* __restrict__ wk,
                    const float* __restrict__ wv, const float* __restrict__ wo,
                    unsigned short* __restrict__ xb,
                    unsigned short* __restrict__ wqkvb,
                    unsigned short* __restrict__ wob)
{
    const unsigned e = (blockIdx.x * 256u + threadIdx.x) * 8u;
    const float* src; unsigned short* dst; unsigned off;
    if      (e < 4194304u) { src = x;  dst = xb;             off = e;            }
    else if (e < 5242880u) { src = wq; dst = wqkvb;          off = e - 4194304u; }
    else if (e < 6291456u) { src = wk; dst = wqkvb+1048576u; off = e - 5242880u; }
    else if (e < 7340032u) { src = wv; dst = wqkvb+2097152u; off = e - 6291456u; }
    else                   { src = wo; dst = wob;            off = e - 7340032u; }
    float4 a = *(const float4*)(src + off);
    float4 b = *(const float4*)(src + off + 4);
    ushort4 u0, u1;
    u0.x=f2bf(a.x); u0.y=f2bf(a.y); u0.z=f2bf(a.z); u0.w=f2bf(a.w);
    u1.x=f2bf(b.x); u1.y=f2bf(b.y); u1.z=f2bf(b.z); u1.w=f2bf(b.w);
    *(ushort4*)(dst + off)     = u0;
    *(ushort4*)(dst + off + 4) = u1;
}

// ---------------------------------------------------------------------------
// bf16 MFMA GEMM: Y[M][NCOLS] = A[M][1024] @ B[NCOLS][1024]^T
// m97 structure: 128x128 tile, BK=32, global_load_lds w=16, 2-barrier K-loop.
// ---------------------------------------------------------------------------
template<int NCOLS, int ROPE, int BF16OUT>
__global__ __launch_bounds__(256)
void gemm_mfma_bt(const unsigned short* __restrict__ A,
                  const unsigned short* __restrict__ B,
                  void* __restrict__ Yv)
{
    __shared__ unsigned short As[128*32];
    __shared__ unsigned short Bs[128*32];

    const int t    = threadIdx.x;
    const int w    = t >> 6;
    const int lane = t & 63;
    const int lq   = lane >> 4;
    const int ln   = lane & 15;
    const int wr   = w >> 1;
    const int wc   = w & 1;
    const int m0   = blockIdx.y * 128;
    const int n0   = blockIdx.x * 128;

    const int srow  = lane >> 2;
    const int kslot = lane & 3;
    const int kk    = kslot ^ ((srow >> 1) & 3);   // XOR k-slot swizzle

    const unsigned short* ga0 = A + (size_t)(m0 + w*16 + srow) * 1024 + kk*8;
    const unsigned short* gb0 = B + (size_t)(n0 + w*16 + srow) * 1024 + kk*8;
    unsigned short* lA = As + w*512;
    unsigned short* lB = Bs + w*512;

    f32x4 acc[4][4];
    #pragma unroll
    for (int mt = 0; mt < 4; ++mt)
        #pragma unroll
        for (int nt = 0; nt < 4; ++nt)
            #pragma unroll
            for (int r = 0; r < 4; ++r) acc[mt][nt][r] = 0.0f;

    const int fslot = (lq ^ ((ln >> 1) & 3)) * 8;

    for (int k0 = 0; k0 < 1024; k0 += 32) {
        __syncthreads();
        async16(ga0 + k0,           lA);
        async16(ga0 + 64*1024 + k0, lA + 2048);
        async16(gb0 + k0,           lB);
        async16(gb0 + 64*1024 + k0, lB + 2048);
        __syncthreads();
        bf16x8 af[4], bf[4];
        #pragma unroll
        for (int i = 0; i < 4; ++i) {
            af[i] = *(const bf16x8*)&As[(wr*64 + i*16 + ln)*32 + fslot];
            bf[i] = *(const bf16x8*)&Bs[(wc*64 + i*16 + ln)*32 + fslot];
        }
        #pragma unroll
        for (int mt = 0; mt < 4; ++mt)
            #pragma unroll
            for (int nt = 0; nt < 4; ++nt)
                acc[mt][nt] = __builtin_amdgcn_mfma_f32_16x16x32_bf16(
                                  af[mt], bf[nt], acc[mt][nt], 0, 0, 0);
    }

    unsigned short* Yb = (unsigned short*)Yv;
    float*          Yf = (float*)Yv;
    const bool doRope = ROPE && (n0 < 2048);
    const float LOG_T = 9.210340371976184f / 32.0f;
    #pragma unroll
    for (int nt = 0; nt < 4; ++nt) {
        const int col = n0 + wc*64 + nt*16 + ln;
        float fr = 0.0f;
        if (doRope) fr = __expf(-(float)((col & 63) >> 1) * LOG_T);
        #pragma unroll
        for (int mt = 0; mt < 4; ++mt) {
            const int row0 = m0 + wr*64 + mt*16 + lq*4;
            #pragma unroll
            for (int r = 0; r < 4; ++r) {
                const float v = acc[mt][nt][r];
                float outv;
                if (doRope) {
                    float sn, cs;
                    __sincosf((float)((row0 + r) & (SEQ - 1)) * fr, &sn, &cs);
                    const float p = __shfl_xor(v, 1);
                    outv = ((ln & 1) == 0) ? (v*cs - p*sn) : (p*sn + v*cs);
                } else {
                    outv = v;
                }
                const size_t yi = (size_t)(row0 + r) * NCOLS + col;
                if (BF16OUT) Yb[yi] = f2bf(outv);
                else         Yf[yi] = outv;
            }
        }
    }
}

// ---------------------------------------------------------------------------
// MFMA flash attention, transposed-P structure. Packed QKV [4096][3072] bf16
// -> Ob [4096][1024] bf16. Block = 64 q rows of one (b,h); 4 waves.
// S^T = K Q^T (C-layout: each lane holds 16 scores for ONE q = lane&15);
// softmax = local reduce + 2 shfl_xor; PV via 16x16x16bf16_1k with P^T
// packed in registers (P^T C-layout == 1k B-fragment layout). 2 barriers/tile,
// K/V prefetched into registers during compute.
// ---------------------------------------------------------------------------
__global__ __launch_bounds__(256)
void flash_mfma_kernel(const unsigned short* __restrict__ QKV,
                       unsigned short* __restrict__ Ob)
{
    __shared__ unsigned short Kt[64 * PITCH];
    __shared__ unsigned short Vt[64 * PITCH];   // V transposed [d][s]
    __shared__ unsigned short Ps[64 * PITCH];   // Q staging, then O transpose

    const int t    = threadIdx.x;
    const int w    = t >> 6;
    const int lane = t & 63;
    const int lq   = lane >> 4;
    const int ln   = lane & 15;
    const int bh   = blockIdx.x;
    const int qb   = (int)gridDim.y - 1 - blockIdx.y;   // heavy first
    const int b    = bh >> 4;
    const int h    = bh & 15;
    const int LD   = 3072;

    const unsigned short* Qg = QKV + h*DK;
    const unsigned short* Kg = QKV + 1024 + h*DK;
    const unsigned short* Vg = QKV + 2048 + h*DK;

    const int sr = t >> 2;            // staging row 0..63
    const int sc = (t & 3) * 16;      // staging col 0,16,32,48
    const int vr = lane;              // V staging: lane-contiguous LDS writes

    // --- stage Q, build B-operand fragments (n = q)
    {
        const unsigned short* qp = Qg + (size_t)(b*SEQ + qb*64 + sr) * LD + sc;
        *(float4*)&Ps[sr*PITCH + sc]     = *(const float4*)qp;
        *(float4*)&Ps[sr*PITCH + sc + 8] = *(const float4*)(qp + 8);
    }
    __syncthreads();
    const bf16x8 qf0 = *(const bf16x8*)&Ps[(w*16 + ln)*PITCH + lq*8];
    const bf16x8 qf1 = *(const bf16x8*)&Ps[(w*16 + ln)*PITCH + 32 + lq*8];

    f32x4 oacc[4];     // O^T: d = dt*16 + lq*4 + r, q = ln (per wave)
    #pragma unroll
    for (int dt = 0; dt < 4; ++dt)
        #pragma unroll
        for (int r = 0; r < 4; ++r) oacc[dt][r] = 0.0f;

    float m_r = -INFINITY, l_r = 0.0f;          // one q per lane now
    const int qg = qb*64 + w*16 + ln;           // this lane's q row

    float4 kA, kB, vA, vB;
    {   // preload tile 0
        const unsigned short* kp = Kg + (size_t)(b*SEQ + sr) * LD + sc;
        kA = *(const float4*)kp;  kB = *(const float4*)(kp + 8);
        const unsigned short* vp = Vg + (size_t)(b*SEQ + vr) * LD + w*16;
        vA = *(const float4*)vp;  vB = *(const float4*)(vp + 8);
    }

    for (int kt = 0; kt <= qb; ++kt) {
        __syncthreads();                         // prev tile consumed
        *(float4*)&Kt[sr*PITCH + sc]     = kA;
        *(float4*)&Kt[sr*PITCH + sc + 8] = kB;
        {
            const unsigned short* va = (const unsigned short*)&vA;
            const unsigned short* vb = (const unsigned short*)&vB;
            #pragma unroll
            for (int i = 0; i < 8; ++i) Vt[(w*16 + i)*PITCH + vr]     = va[i];
            #pragma unroll
            for (int i = 0; i < 8; ++i) Vt[(w*16 + 8 + i)*PITCH + vr] = vb[i];
        }
        __syncthreads();                         // tile visible

        if (kt < qb) {                           // prefetch next (drains at next barrier)
            const unsigned short* kp = Kg + (size_t)(b*SEQ + (kt+1)*64 + sr) * LD + sc;
            kA = *(const float4*)kp;  kB = *(const float4*)(kp + 8);
            const unsigned short* vp = Vg + (size_t)(b*SEQ + (kt+1)*64 + vr) * LD + w*16;
            vA = *(const float4*)vp;  vB = *(const float4*)(vp + 8);
        }

        // --- S^T = K Q^T  (A = K frag, B = Q frag)
        f32x4 sacc[4];
        #pragma unroll
        for (int nt = 0; nt < 4; ++nt) {
            #pragma unroll
            for (int r = 0; r < 4; ++r) sacc[nt][r] = 0.0f;
            bf16x8 kf0 = *(const bf16x8*)&Kt[(nt*16 + ln)*PITCH + lq*8];
            bf16x8 kf1 = *(const bf16x8*)&Kt[(nt*16 + ln)*PITCH + 32 + lq*8];
            sacc[nt] = __builtin_amdgcn_mfma_f32_16x16x32_bf16(kf0, qf0, sacc[nt], 0, 0, 0);
            sacc[nt] = __builtin_amdgcn_mfma_f32_16x16x32_bf16(kf1, qf1, sacc[nt], 0, 0, 0);
        }

        // --- online softmax: 16 scores per lane, all for q = qg
        float sv[16];
        const bool diag = (kt == qb);
        #pragma unroll
        for (int nt = 0; nt < 4; ++nt)
            #pragma unroll
            for (int r = 0; r < 4; ++r) {
                float s = sacc[nt][r] * 0.125f;
                if (diag && (kt*64 + nt*16 + lq*4 + r > qg)) s = -INFINITY;
                sv[nt*4 + r] = s;
            }
        float tm = sv[0];
        #pragma unroll
        for (int i = 1; i < 16; ++i) tm = fmaxf(tm, sv[i]);
        tm = fmaxf(tm, __shfl_xor(tm, 16));
        tm = fmaxf(tm, __shfl_xor(tm, 32));
        const float mnew  = fmaxf(m_r, tm);
        const float alpha = __expf(m_r - mnew);   // 0 on first tile
        float p[16], sum = 0.0f;
        #pragma unroll
        for (int i = 0; i < 16; ++i) { p[i] = __expf(sv[i] - mnew); sum += p[i]; }
        sum += __shfl_xor(sum, 16);
        sum += __shfl_xor(sum, 32);
        l_r = l_r * alpha + sum;
        m_r = mnew;
        #pragma unroll
        for (int dt = 0; dt < 4; ++dt)
            #pragma unroll
            for (int r = 0; r < 4; ++r) oacc[dt][r] *= alpha;

        // --- pack P^T fragments (C-layout == 1k B-fragment layout)
        s16x4 pf[4];
        #pragma unroll
        for (int ks = 0; ks < 4; ++ks)
            #pragma unroll
            for (int r = 0; r < 4; ++r)
                pf[ks][r] = (short)f2bf(p[ks*4 + r]);

        // --- O^T += V^T P^T  (16 x mfma_16x16x16, K=16 keys each)
        #pragma unroll
        for (int dt = 0; dt < 4; ++dt)
            #pragma unroll
            for (int ks = 0; ks < 4; ++ks) {
                s16x4 vf = *(const s16x4*)&Vt[(dt*16 + ln)*PITCH + ks*16 + lq*4];
                oacc[dt] = __builtin_amdgcn_mfma_f32_16x16x16bf16_1k(
                               vf, pf[ks], oacc[dt], 0, 0, 0);
            }
    }

    // --- epilogue: normalize, transpose via LDS, coalesced store
    const float linv = 1.0f / l_r;
    #pragma unroll
    for (int dt = 0; dt < 4; ++dt)
        #pragma unroll
        for (int r = 0; r < 4; ++r)
            Ps[(w*16 + ln)*PITCH + dt*16 + lq*4 + r] = f2bf(oacc[dt][r] * linv);
    __syncthreads();
    {
        unsigned short* op = Ob + (size_t)(b*SEQ + qb*64 + sr) * DMODEL + h*DK + sc;
        *(float4*)(op)     = *(const float4*)&Ps[sr*PITCH + sc];
        *(float4*)(op + 8) = *(const float4*)&Ps[sr*PITCH + sc + 8];
    }
}

// ---------------------------------------------------------------------------
extern "C" void kernel_launch(void* const* d_in, const int* in_sizes, int n_in,
                              void* d_out, int out_size, void* d_ws, size_t ws_size,
                              hipStream_t stream)
{
    const float* x  = (const float*)d_in[0];
    const float* Wq = (const float*)d_in[1];
    const float* Wk = (const float*)d_in[2];
    const float* Wv = (const float*)d_in[3];
    const float* Wo = (const float*)d_in[4];
    float* out = (float*)d_out;

    unsigned short* xb    = (unsigned short*)d_ws;   //  4M elems
    unsigned short* wqkvb = xb + 4194304;            //  3M
    unsigned short* wob   = wqkvb + 3145728;         //  1M
    unsigned short* qkv   = wob + 1048576;           // 12M  [4096][3072]
    unsigned short* ob    = qkv + 12582912;          //  4M  [4096][1024]

    convert_kernel<<<4096, 256, 0, stream>>>(x, Wq, Wk, Wv, Wo, xb, wqkvb, wob);

    gemm_mfma_bt<3072, 1, 1><<<dim3(24, 32), 256, 0, stream>>>(xb, wqkvb, qkv);

    flash_mfma_kernel<<<dim3(32, 32), 256, 0, stream>>>(qkv, ob);

    gemm_mfma_bt<1024, 0, 0><<<dim3(8, 32), 256, 0, stream>>>(ob, wob, out);
}